// Round 1
// baseline (39.647 us; speedup 1.0000x reference)
//
#include <hip/hip_runtime.h>
#include <math.h>

// Problem constants
#define Bq 64
#define Nq 256
#define Dq 512
#define Vq 50257
#define Kq 100
#define KP 112              // K padded to 7*16
#define NKT 7               // k-tiles of 16
#define NDT 16              // d-tiles of 32 (512/32)
#define NORM_TERM 10.8249051f   // log(50257)
#define LOGK 4.6051702f         // log(100)

typedef __attribute__((ext_vector_type(8))) short short8;
typedef __attribute__((ext_vector_type(4))) float floatx4;

__device__ __forceinline__ unsigned short f2bf(float f) {
    union { float f; unsigned u; } v; v.f = f;
    unsigned r = v.u + 0x7FFFu + ((v.u >> 16) & 1u);   // RNE
    return (unsigned short)(r >> 16);
}

__device__ __forceinline__ float dot4(floatx4 a, floatx4 b) {
    return a.x*b.x + a.y*b.y + a.z*b.z + a.w*b.w;
}

__device__ __forceinline__ float log_sigmoid(float x) {
    // log(sigmoid(x)) = min(x,0) - log1p(exp(-|x|))
    return fminf(x, 0.f) - log1pf(expf(-fabsf(x)));
}

// Gather + convert noise embedding rows to bf16 [112][512], zero-padded.
// Also precompute per-noise adjustment: bias - NORM - logprob_noise - logK.
__global__ void prep_noise(const float* __restrict__ emb_w,
                           const float* __restrict__ emb_b,
                           const float* __restrict__ lpn,
                           const int* __restrict__ ns,
                           unsigned short* __restrict__ nB,
                           float* __restrict__ nAdj) {
    int k = blockIdx.x;     // 0..111
    int t = threadIdx.x;    // 0..63
    if (k < Kq) {
        int row = ns[k];
        const float* src = emb_w + (size_t)row * Dq;
        for (int i = t; i < Dq; i += 64) nB[k * Dq + i] = f2bf(src[i]);
        if (t == 0) nAdj[k] = emb_b[row] - NORM_TERM - lpn[row] - LOGK;
    } else {
        for (int i = t; i < Dq; i += 64) nB[k * Dq + i] = 0;
        if (t == 0) nAdj[k] = 0.f;
    }
}

// One wave = 16 consecutive positions (all same batch b).
//  - loads each input row once (fp32), fuses: fp32 target dot + bf16 A-frags
//  - noise logits via mfma_f32_16x16x32_bf16 against L2-resident noise tile
//  - epilogue: log-sigmoid sums, wave-reduce, one partial per wave
__global__ __launch_bounds__(256) void nce_main(
    const float* __restrict__ input,     // [16384][512]
    const float* __restrict__ emb_w,     // [V][512]
    const float* __restrict__ emb_b,     // [V]
    const float* __restrict__ lpn,       // [V]
    const int* __restrict__ target,      // [16384]
    const unsigned short* __restrict__ nB,   // [112][512] bf16
    const float* __restrict__ nAdj,          // [112]
    float* __restrict__ partials)            // [1024]
{
    int tid  = threadIdx.x;
    int lane = tid & 63;
    int wid  = (int)blockIdx.x * 4 + (tid >> 6);  // global wave id 0..1023
    int pos0 = wid * 16;
    int r16  = lane & 15;   // A row (position-in-tile) / B col (noise idx)
    int g4   = lane >> 4;   // k-group within d-tile

    int mypos = pos0 + r16;
    int tgt   = target[mypos];
    const float* inrow = input + (size_t)mypos * Dq;
    const float* trow  = emb_w + (size_t)tgt  * Dq;

    // Load input row chunks once: fp32 target dot + bf16 A fragments.
    short8 afrag[NDT];
    float acc_t = 0.f;
#pragma unroll
    for (int dt = 0; dt < NDT; ++dt) {
        int d0 = dt * 32 + g4 * 8;
        floatx4 x0 = *(const floatx4*)(inrow + d0);
        floatx4 x1 = *(const floatx4*)(inrow + d0 + 4);
        floatx4 t0 = *(const floatx4*)(trow + d0);
        floatx4 t1 = *(const floatx4*)(trow + d0 + 4);
        acc_t += dot4(x0, t0) + dot4(x1, t1);
        short8 a;
        a[0] = (short)f2bf(x0.x); a[1] = (short)f2bf(x0.y);
        a[2] = (short)f2bf(x0.z); a[3] = (short)f2bf(x0.w);
        a[4] = (short)f2bf(x1.x); a[5] = (short)f2bf(x1.y);
        a[6] = (short)f2bf(x1.z); a[7] = (short)f2bf(x1.w);
        afrag[dt] = a;
    }
    // lanes {r16, r16+16, r16+32, r16+48} jointly hold the full row dot
    acc_t += __shfl_xor(acc_t, 16);
    acc_t += __shfl_xor(acc_t, 32);

    floatx4 acc[NKT];
#pragma unroll
    for (int kt = 0; kt < NKT; ++kt) {
        acc[kt].x = 0.f; acc[kt].y = 0.f; acc[kt].z = 0.f; acc[kt].w = 0.f;
    }

#pragma unroll
    for (int kt = 0; kt < NKT; ++kt) {
        const unsigned short* brow = nB + (size_t)(kt * 16 + r16) * Dq;
#pragma unroll
        for (int dt = 0; dt < NDT; ++dt) {
            short8 bfr = *(const short8*)(brow + dt * 32 + g4 * 8);
            acc[kt] = __builtin_amdgcn_mfma_f32_16x16x32_bf16(
                afrag[dt], bfr, acc[kt], 0, 0, 0);
        }
    }

    // Epilogue. D mapping (HW-verified): col = lane&15, row = (lane>>4)*4 + reg.
    // row = position-in-tile, col = noise index within k-tile.
    float contrib = 0.f;
#pragma unroll
    for (int kt = 0; kt < NKT; ++kt) {
        int k = kt * 16 + r16;
        if (k < Kq) {
            float adj = nAdj[k];
#pragma unroll
            for (int r = 0; r < 4; ++r)
                contrib += log_sigmoid(-(acc[kt][r] + adj));
        }
    }
    if (g4 == 0) {  // lanes 0..15 each own one position's target term
        float xt = acc_t + emb_b[tgt] - NORM_TERM - lpn[tgt] - LOGK;
        contrib += log_sigmoid(xt);
    }
#pragma unroll
    for (int off = 32; off >= 1; off >>= 1)
        contrib += __shfl_xor(contrib, off);
    if (lane == 0) partials[wid] = contrib;
}

// Deterministic per-batch reduction: out[b] = sum of 16 wave partials.
__global__ void finalize(const float* __restrict__ partials,
                         float* __restrict__ out) {
    int b = threadIdx.x;  // 0..63
    float s = 0.f;
    for (int i = 0; i < 16; ++i) s += partials[b * 16 + i];
    out[b] = s;
}

extern "C" void kernel_launch(void* const* d_in, const int* in_sizes, int n_in,
                              void* d_out, int out_size, void* d_ws, size_t ws_size,
                              hipStream_t stream) {
    const float* input = (const float*)d_in[0];
    const float* emb_w = (const float*)d_in[1];
    const float* emb_b = (const float*)d_in[2];
    const float* lpn   = (const float*)d_in[3];
    const int*   tgt   = (const int*)d_in[4];
    const int*   ns    = (const int*)d_in[5];
    float* out = (float*)d_out;

    // ws layout: [0, 114688) noise bf16; [114688, 115136) nAdj; [115200, ...) partials
    unsigned short* nB  = (unsigned short*)d_ws;
    float* nAdj     = (float*)((char*)d_ws + (size_t)KP * Dq * 2);
    float* partials = (float*)((char*)d_ws + (size_t)KP * Dq * 2 + 512);

    prep_noise<<<KP, 64, 0, stream>>>(emb_w, emb_b, lpn, ns, nB, nAdj);
    nce_main<<<256, 256, 0, stream>>>(input, emb_w, emb_b, lpn, tgt, nB, nAdj, partials);
    finalize<<<1, 64, 0, stream>>>(partials, out);
}